// Round 1
// baseline (331.022 us; speedup 1.0000x reference)
//
#include <hip/hip_runtime.h>
#include <math.h>

// Delta-rule linear attention, chunked-parallel formulation.
// B=8, S=4096, D=256, chunk L=64 -> C=64 chunks/batch, 512 chunks total.
// ws layout: A/H buffer [512][256][256] f32 (128 MiB) + P [512] f32.

#define B_ 8
#define S_ 4096
#define D_ 256
#define L_ 64
#define C_ (S_ / L_)     // 64
#define BC_ (B_ * C_)    // 512
#define TS1 16           // s-tile in k_summary
#define DK3 32           // d-tile in k_output phase A
#define KT3 32           // k-tile in k_output phase B

// ---------------------------------------------------------------------------
// Kernel 1: per-chunk decayed summary  A_c[i][j] = sum_s w_s k_s[i] v_s[j],
// w_s = prod_{j>s} beta_j ; P_c = prod_s beta_s.
// ---------------------------------------------------------------------------
__global__ __launch_bounds__(1024) void k_summary(
    const float* __restrict__ kg, const float* __restrict__ vg,
    const float* __restrict__ beta, float* __restrict__ A,
    float* __restrict__ P)
{
  __shared__ float ls[L_];
  __shared__ float wv[L_];
  __shared__ __align__(16) float kt[TS1][D_ + 4];
  __shared__ __align__(16) float vt[TS1][D_ + 4];

  const int bc = blockIdx.x;
  const int b = bc / C_, c = bc % C_;
  const int tid = threadIdx.x;
  const float* betap = beta + (size_t)b * S_ + (size_t)c * L_;

  if (tid < L_) wv[tid] = betap[tid];          // parallel beta load
  __syncthreads();
  if (tid == 0) {                              // prefix log2 sums
    float acc = 0.f;
    for (int t = 0; t < L_; ++t) {
      acc += log2f(fmaxf(wv[t], 1e-30f));
      ls[t] = acc;
    }
  }
  __syncthreads();
  const float ltot = ls[L_ - 1];
  if (tid < L_) wv[tid] = exp2f(ltot - ls[tid]);   // suffix decay weights
  if (tid == 0) P[bc] = exp2f(ltot);

  const int ib = tid >> 5;   // 0..31 row block
  const int jb = tid & 31;   // 0..31 col block
  float acc[8][8];
#pragma unroll
  for (int a = 0; a < 8; ++a)
#pragma unroll
    for (int d = 0; d < 8; ++d) acc[a][d] = 0.f;

  const float* kbase = kg + ((size_t)b * S_ + (size_t)c * L_) * D_;
  const float* vbase = vg + ((size_t)b * S_ + (size_t)c * L_) * D_;

  for (int st = 0; st < L_ / TS1; ++st) {
    __syncthreads();   // protects LDS reuse and the wv[] write above
    {
      const int half = tid >> 9;        // 0: k-tile, 1: v-tile
      const int t2 = tid & 511;
      const int row = t2 >> 5;          // 0..15
      const int col = (t2 & 31) * 8;    // 0..248
      const int srow = st * TS1 + row;
      if (half == 0) {
        const float* src = kbase + (size_t)srow * D_ + col;
        float4 a0 = ((const float4*)src)[0];
        float4 a1 = ((const float4*)src)[1];
        const float w = wv[srow];
        a0.x *= w; a0.y *= w; a0.z *= w; a0.w *= w;
        a1.x *= w; a1.y *= w; a1.z *= w; a1.w *= w;
        *(float4*)&kt[row][col] = a0;
        *(float4*)&kt[row][col + 4] = a1;
      } else {
        const float* src = vbase + (size_t)srow * D_ + col;
        float4 a0 = ((const float4*)src)[0];
        float4 a1 = ((const float4*)src)[1];
        *(float4*)&vt[row][col] = a0;
        *(float4*)&vt[row][col + 4] = a1;
      }
    }
    __syncthreads();
#pragma unroll
    for (int s = 0; s < TS1; ++s) {
      float kr[8], vr[8];
      *(float4*)&kr[0] = *(float4*)&kt[s][ib * 8];
      *(float4*)&kr[4] = *(float4*)&kt[s][ib * 8 + 4];
      *(float4*)&vr[0] = *(float4*)&vt[s][jb * 8];
      *(float4*)&vr[4] = *(float4*)&vt[s][jb * 8 + 4];
#pragma unroll
      for (int a = 0; a < 8; ++a)
#pragma unroll
        for (int d = 0; d < 8; ++d)
          acc[a][d] = fmaf(kr[a], vr[d], acc[a][d]);
    }
  }

  float* Ab = A + (size_t)bc * D_ * D_;
#pragma unroll
  for (int a = 0; a < 8; ++a) {
    const int i = ib * 8 + a;
    *(float4*)(Ab + (size_t)i * D_ + jb * 8) =
        make_float4(acc[a][0], acc[a][1], acc[a][2], acc[a][3]);
    *(float4*)(Ab + (size_t)i * D_ + jb * 8 + 4) =
        make_float4(acc[a][4], acc[a][5], acc[a][6], acc[a][7]);
  }
}

// ---------------------------------------------------------------------------
// Kernel 2: in-place scan over chunks. On exit A[bc] holds the state H
// ENTERING chunk c:  H_0 = 0 ; H_c = P_{c-1} H_{c-1} + A_{c-1}.
// One thread per (b, i, j) element; 64 sequential chunk steps.
// ---------------------------------------------------------------------------
__global__ void k_scan(float* __restrict__ A, const float* __restrict__ P)
{
  const int b = blockIdx.x >> 8;                       // 256 blocks / batch
  const int idx = ((blockIdx.x & 255) << 8) + threadIdx.x;   // 0..65535
  const size_t stride = (size_t)D_ * D_;
  const size_t base = (size_t)b * C_ * stride + idx;
  float h = 0.f;
  for (int c = 0; c < C_; ++c) {
    const size_t off = base + (size_t)c * stride;
    const float a = A[off];
    A[off] = h;
    h = fmaf(P[b * C_ + c], h, a);
  }
}

// ---------------------------------------------------------------------------
// Kernel 3: per-chunk output
//   O[t][j] = sum_s TmT[s][t] V[s][j] + sum_i (c_t q[t][i]) H[i][j]
//   TmT[s][t] = (s<=t) ? exp2(Ls[t]-Ls[s]) * (q_t . k_s) : 0
// ---------------------------------------------------------------------------
__global__ __launch_bounds__(512) void k_output(
    const float* __restrict__ qg, const float* __restrict__ kg,
    const float* __restrict__ vg, const float* __restrict__ beta,
    const float* __restrict__ Hg, float* __restrict__ outg)
{
  __shared__ float ls[L_];
  __shared__ float cv[L_];
  __shared__ __align__(16) float TmT[L_][L_ + 4];   // [s][t]
  __shared__ __align__(16) float Rt[KT3][D_ + 4];   // right tile (V or H rows)
  __shared__ __align__(16) float QcT[DK3][L_ + 4];  // [i][t]; reused as qT in A

  const int bc = blockIdx.x;
  const int b = bc / C_, c = bc % C_;
  const int tid = threadIdx.x;

  const float* betap = beta + (size_t)b * S_ + (size_t)c * L_;
  const float* qbase = qg + ((size_t)b * S_ + (size_t)c * L_) * D_;
  const float* kbase = kg + ((size_t)b * S_ + (size_t)c * L_) * D_;
  const float* vbase = vg + ((size_t)b * S_ + (size_t)c * L_) * D_;
  const float* Hbase = Hg + (size_t)bc * D_ * D_;

  if (tid < L_) cv[tid] = betap[tid];
  __syncthreads();
  if (tid == 0) {
    float acc = 0.f;
    for (int t = 0; t < L_; ++t) {
      acc += log2f(fmaxf(cv[t], 1e-30f));
      ls[t] = acc;
    }
  }
  __syncthreads();
  if (tid < L_) cv[tid] = exp2f(ls[tid]);   // c_t (inclusive cumprod)

  // -------- phase A: T = Q K^T over d=256, d-major LDS tiles ---------------
  float accT[4][4];
#pragma unroll
  for (int a = 0; a < 4; ++a)
#pragma unroll
    for (int d = 0; d < 4; ++d) accT[a][d] = 0.f;
  const int tbA = (tid >> 4) & 15;   // threads 0..255 compute 4x4 tiles
  const int sbA = tid & 15;
  float (*kTt)[L_ + 4] = (float (*)[L_ + 4])&Rt[0][0];  // alias: fits in Rt

  for (int dt = 0; dt < D_ / DK3; ++dt) {
    __syncthreads();
    {
      const int half = tid >> 8;      // 0: q-tile, 1: k-tile
      const int t2 = tid & 255;
      const int trow = t2 >> 2;       // 0..63
      const int dd0 = (t2 & 3) * 8;   // 0,8,16,24
      const float* src =
          (half == 0 ? qbase : kbase) + (size_t)trow * D_ + dt * DK3 + dd0;
      float4 a0 = ((const float4*)src)[0];
      float4 a1 = ((const float4*)src)[1];
      float vals[8] = {a0.x, a0.y, a0.z, a0.w, a1.x, a1.y, a1.z, a1.w};
      if (half == 0) {
#pragma unroll
        for (int u = 0; u < 8; ++u) QcT[dd0 + u][trow] = vals[u];
      } else {
#pragma unroll
        for (int u = 0; u < 8; ++u) kTt[dd0 + u][trow] = vals[u];
      }
    }
    __syncthreads();
    if (tid < 256) {
#pragma unroll
      for (int dd = 0; dd < DK3; ++dd) {
        float qr[4], kr[4];
        *(float4*)&qr[0] = *(float4*)&QcT[dd][tbA * 4];
        *(float4*)&kr[0] = *(float4*)&kTt[dd][sbA * 4];
#pragma unroll
        for (int a = 0; a < 4; ++a)
#pragma unroll
          for (int d = 0; d < 4; ++d)
            accT[a][d] = fmaf(qr[a], kr[d], accT[a][d]);
      }
    }
  }
  __syncthreads();
  if (tid < 256) {   // decay + causal mask, store transposed
#pragma unroll
    for (int a = 0; a < 4; ++a) {
      const int t = tbA * 4 + a;
#pragma unroll
      for (int d = 0; d < 4; ++d) {
        const int s = sbA * 4 + d;
        const float m = (s <= t) ? exp2f(ls[t] - ls[s]) : 0.f;
        TmT[s][t] = m * accT[a][d];
      }
    }
  }

  // -------- phase B: O = [Tm | c.Q] @ [V ; H] ------------------------------
  const int tb = tid >> 6;       // 0..7 -> 8 t-rows
  const int jbB = tid & 63;      // 0..63 -> 4 j-cols
  const int t0 = tb * 8;
  const int j0 = jbB * 4;
  float accO[8][4];
#pragma unroll
  for (int a = 0; a < 8; ++a)
#pragma unroll
    for (int d = 0; d < 4; ++d) accO[a][d] = 0.f;

  for (int kt2 = 0; kt2 < (L_ + D_) / KT3; ++kt2) {   // 10 tiles
    __syncthreads();
    if (kt2 < L_ / KT3) {
      // stage V rows s = kt2*32 .. +31
      const int row = tid >> 4;
      const int col0 = (tid & 15) * 16;
      const float* src = vbase + (size_t)(kt2 * KT3 + row) * D_ + col0;
#pragma unroll
      for (int u = 0; u < 4; ++u)
        *(float4*)&Rt[row][col0 + u * 4] = ((const float4*)src)[u];
    } else {
      const int i0 = (kt2 - L_ / KT3) * KT3;
      {
        const int row = tid >> 4;
        const int col0 = (tid & 15) * 16;
        const float* src = Hbase + (size_t)(i0 + row) * D_ + col0;
#pragma unroll
        for (int u = 0; u < 4; ++u)
          *(float4*)&Rt[row][col0 + u * 4] = ((const float4*)src)[u];
      }
      {
        const int t = tid >> 3;           // 0..63
        const int io = (tid & 7) * 4;     // 0..28
        const float4 qv = *(const float4*)(qbase + (size_t)t * D_ + i0 + io);
        const float ct = cv[t];
        QcT[io + 0][t] = ct * qv.x;
        QcT[io + 1][t] = ct * qv.y;
        QcT[io + 2][t] = ct * qv.z;
        QcT[io + 3][t] = ct * qv.w;
      }
    }
    __syncthreads();
    const bool isS = kt2 < L_ / KT3;
#pragma unroll
    for (int r = 0; r < KT3; ++r) {
      float lv[8], rv[4];
      if (isS) {
        *(float4*)&lv[0] = *(float4*)&TmT[kt2 * KT3 + r][t0];
        *(float4*)&lv[4] = *(float4*)&TmT[kt2 * KT3 + r][t0 + 4];
      } else {
        *(float4*)&lv[0] = *(float4*)&QcT[r][t0];
        *(float4*)&lv[4] = *(float4*)&QcT[r][t0 + 4];
      }
      *(float4*)&rv[0] = *(float4*)&Rt[r][j0];
#pragma unroll
      for (int a = 0; a < 8; ++a)
#pragma unroll
        for (int d = 0; d < 4; ++d)
          accO[a][d] = fmaf(lv[a], rv[d], accO[a][d]);
    }
  }

  float* ob = outg + ((size_t)b * S_ + (size_t)c * L_) * D_;
#pragma unroll
  for (int a = 0; a < 8; ++a)
    *(float4*)(ob + (size_t)(t0 + a) * D_ + j0) =
        make_float4(accO[a][0], accO[a][1], accO[a][2], accO[a][3]);
}

// ---------------------------------------------------------------------------
extern "C" void kernel_launch(void* const* d_in, const int* in_sizes, int n_in,
                              void* d_out, int out_size, void* d_ws,
                              size_t ws_size, hipStream_t stream) {
  const float* q = (const float*)d_in[0];
  const float* k = (const float*)d_in[1];
  const float* v = (const float*)d_in[2];
  const float* beta = (const float*)d_in[3];
  float* out = (float*)d_out;

  // workspace: A/H buffer (128 MiB) then P (2 KiB)
  float* A = (float*)d_ws;
  float* P = (float*)((char*)d_ws + (size_t)BC_ * D_ * D_ * sizeof(float));

  k_summary<<<dim3(BC_), dim3(1024), 0, stream>>>(k, v, beta, A, P);
  k_scan<<<dim3(B_ * (D_ * D_ / 256)), dim3(256), 0, stream>>>(A, P);
  k_output<<<dim3(BC_), dim3(512), 0, stream>>>(q, k, v, beta, A, out);
}

// Round 2
// 216.612 us; speedup vs baseline: 1.5282x; 1.5282x over previous
//
#include <hip/hip_runtime.h>
#include <math.h>

// Delta-rule linear attention, chunked + MFMA bf16, bf16 state buffer.
// B=8, S=4096, D=256, L=64 -> C=64 chunks/batch, 512 chunks total.
// ws: A/H buffer [512][256][256] bf16 in TRANSPOSED [j][i] layout (64 MiB),
//     then P [512] f32.

#define B_ 8
#define S_ 4096
#define D_ 256
#define L_ 64
#define C_ (S_ / L_)
#define BC_ (B_ * C_)

typedef __attribute__((ext_vector_type(8))) short s8v;   // 8 bf16 (4 VGPR)
typedef __attribute__((ext_vector_type(4))) float f4v;   // MFMA acc
typedef unsigned short u16;
typedef unsigned int u32;

__device__ __forceinline__ u16 f2bf(float f) {           // RNE f32->bf16
  u32 u = __float_as_uint(f);
  u += 0x7FFF + ((u >> 16) & 1);
  return (u16)(u >> 16);
}
__device__ __forceinline__ s8v pack8(float4 a, float4 b) {
  s8v r;
  r[0] = (short)f2bf(a.x); r[1] = (short)f2bf(a.y);
  r[2] = (short)f2bf(a.z); r[3] = (short)f2bf(a.w);
  r[4] = (short)f2bf(b.x); r[5] = (short)f2bf(b.y);
  r[6] = (short)f2bf(b.z); r[7] = (short)f2bf(b.w);
  return r;
}

// ---------------------------------------------------------------------------
// Kernel 1: Astore[bc][j][i] = sum_s w_s k_s[i] v_s[j]  (bf16 out, [j][i]!)
//           P[bc] = prod_s beta_s.  MFMA: M=j (A-op=V^T), N=i (B-op=K^T*w).
// ---------------------------------------------------------------------------
__global__ __launch_bounds__(256, 2) void ks_summary2(
    const float* __restrict__ kg, const float* __restrict__ vg,
    const float* __restrict__ beta, u16* __restrict__ A,
    float* __restrict__ P)
{
  __shared__ float ls[L_];
  __shared__ u16 KT[D_][72];   // [i][s] bf16, w-scaled
  __shared__ u16 VT[D_][72];   // [j][s] bf16

  const int bc = blockIdx.x;
  const int b = bc / C_, c = bc % C_;
  const int tid = threadIdx.x;
  const float* betap = beta + (size_t)b * S_ + (size_t)c * L_;
  const float* kbase = kg + ((size_t)b * S_ + (size_t)c * L_) * D_;
  const float* vbase = vg + ((size_t)b * S_ + (size_t)c * L_) * D_;

  if (tid < L_) ls[tid] = betap[tid];
  __syncthreads();
  if (tid == 0) {
    float a = 0.f;
    for (int t = 0; t < L_; ++t) { a += log2f(fmaxf(ls[t], 1e-30f)); ls[t] = a; }
  }
  __syncthreads();
  const float ltot = ls[L_ - 1];
  if (tid == 0) P[bc] = exp2f(ltot);

  // ---- stage transposed bf16 tiles (u32-pair LDS writes) ----
  {
    const int iL = tid & 7;          // i subgroup
    const int sP = tid >> 3;         // 0..31 -> s pair
    const int s0 = sP * 2;
    const float w0 = exp2f(ltot - ls[s0]);
    const float w1 = exp2f(ltot - ls[s0 + 1]);
    const float* k0 = kbase + (size_t)s0 * D_;
    const float* k1 = kbase + (size_t)(s0 + 1) * D_;
    const float* v0 = vbase + (size_t)s0 * D_;
    const float* v1 = vbase + (size_t)(s0 + 1) * D_;
#pragma unroll
    for (int pass = 0; pass < 8; ++pass) {
      const int i0 = pass * 32 + iL * 4;
      float ka[4], kb[4], va[4], vb[4];
      *(float4*)ka = *(const float4*)(k0 + i0);
      *(float4*)kb = *(const float4*)(k1 + i0);
      *(float4*)va = *(const float4*)(v0 + i0);
      *(float4*)vb = *(const float4*)(v1 + i0);
#pragma unroll
      for (int u = 0; u < 4; ++u) {
        *(u32*)&KT[i0 + u][s0] =
            (u32)f2bf(ka[u] * w0) | ((u32)f2bf(kb[u] * w1) << 16);
        *(u32*)&VT[i0 + u][s0] =
            (u32)f2bf(va[u]) | ((u32)f2bf(vb[u]) << 16);
      }
    }
  }
  __syncthreads();

  const int lane = tid & 63, wave = tid >> 6;
  const int quad = lane >> 4, l15 = lane & 15;
  const int m0 = wave * 64;                 // j-strip for this wave
  u16* Ab = A + (size_t)bc * D_ * D_;

  for (int ng = 0; ng < 4; ++ng) {          // i-groups of 64
    f4v acc[4][4];
#pragma unroll
    for (int mt = 0; mt < 4; ++mt)
#pragma unroll
      for (int nt = 0; nt < 4; ++nt) acc[mt][nt] = (f4v){0.f, 0.f, 0.f, 0.f};

#pragma unroll
    for (int ks = 0; ks < 2; ++ks) {
      const int so = ks * 32 + quad * 8;
      s8v av[4], bv[4];
#pragma unroll
      for (int mt = 0; mt < 4; ++mt)
        av[mt] = *(const s8v*)&VT[m0 + mt * 16 + l15][so];
#pragma unroll
      for (int nt = 0; nt < 4; ++nt)
        bv[nt] = *(const s8v*)&KT[ng * 64 + nt * 16 + l15][so];
#pragma unroll
      for (int mt = 0; mt < 4; ++mt)
#pragma unroll
        for (int nt = 0; nt < 4; ++nt)
          acc[mt][nt] = __builtin_amdgcn_mfma_f32_16x16x32_bf16(
              av[mt], bv[nt], acc[mt][nt], 0, 0, 0);
    }
    // epilogue: bf16 pair-packed stores, [j][i]
#pragma unroll
    for (int mt = 0; mt < 4; ++mt)
#pragma unroll
      for (int r = 0; r < 4; ++r) {
        const int j = m0 + mt * 16 + quad * 4 + r;
#pragma unroll
        for (int nt = 0; nt < 4; ++nt) {
          const int i = ng * 64 + nt * 16 + l15;
          const float v = acc[mt][nt][r];
          const float o = __shfl_xor(v, 1);
          if (!(lane & 1)) {
            *(u32*)(Ab + (size_t)j * D_ + i) =
                (u32)f2bf(v) | ((u32)f2bf(o) << 16);
          }
        }
      }
  }
}

// ---------------------------------------------------------------------------
// Kernel 2: in-place chunk scan (bf16 state, fp32 accumulate).
// On exit A[bc] holds state ENTERING chunk c.
// ---------------------------------------------------------------------------
__global__ __launch_bounds__(256) void ks_scan2(
    u16* __restrict__ A, const float* __restrict__ P)
{
  const int b = blockIdx.x >> 6;                               // 64 blk/batch
  const int grp = ((blockIdx.x & 63) << 8) + threadIdx.x;      // 0..16383
  const size_t base = (size_t)b * (C_ * (size_t)D_ * D_) + (size_t)grp * 4;
  const float* Pb = P + b * C_;
  float h0 = 0.f, h1 = 0.f, h2 = 0.f, h3 = 0.f;
#pragma unroll 2
  for (int c = 0; c < C_; ++c) {
    u16* p = A + base + (size_t)c * (D_ * D_);
    uint2 u = *(const uint2*)p;
    const float a0 = __uint_as_float(u.x << 16);
    const float a1 = __uint_as_float(u.x & 0xFFFF0000u);
    const float a2 = __uint_as_float(u.y << 16);
    const float a3 = __uint_as_float(u.y & 0xFFFF0000u);
    uint2 w;
    w.x = (u32)f2bf(h0) | ((u32)f2bf(h1) << 16);
    w.y = (u32)f2bf(h2) | ((u32)f2bf(h3) << 16);
    *(uint2*)p = w;
    const float pc = Pb[c];
    h0 = fmaf(pc, h0, a0); h1 = fmaf(pc, h1, a1);
    h2 = fmaf(pc, h2, a2); h3 = fmaf(pc, h3, a3);
  }
}

// ---------------------------------------------------------------------------
// Kernel 3: O = Tm @ V + diag(c) Q @ H.
//  phase A: T = Q K^T (frags straight from global fp32 -> bf16, no LDS).
//  mask/decay -> Tm (fp32 LDS).  phase B: A-ops Tm / Q, B-ops V^T(LDS) /
//  H(global bf16, [j][i] layout == B-operand order).
// ---------------------------------------------------------------------------
__global__ __launch_bounds__(256, 2) void ks_output2(
    const float* __restrict__ qg, const float* __restrict__ kg,
    const float* __restrict__ vg, const float* __restrict__ beta,
    const u16* __restrict__ Hg, float* __restrict__ outg)
{
  __shared__ float ls[L_];
  __shared__ float cv[L_];
  __shared__ u16 VT[D_][72];      // [j][s] bf16
  __shared__ float Tm[L_][68];    // [t][s] fp32

  const int bc = blockIdx.x;
  const int b = bc / C_, c = bc % C_;
  const int tid = threadIdx.x;
  const float* betap = beta + (size_t)b * S_ + (size_t)c * L_;
  const float* qbase = qg + ((size_t)b * S_ + (size_t)c * L_) * D_;
  const float* kbase = kg + ((size_t)b * S_ + (size_t)c * L_) * D_;
  const float* vbase = vg + ((size_t)b * S_ + (size_t)c * L_) * D_;
  const u16* Hb = Hg + (size_t)bc * D_ * D_;

  if (tid < L_) ls[tid] = betap[tid];
  __syncthreads();
  if (tid == 0) {
    float a = 0.f;
    for (int t = 0; t < L_; ++t) { a += log2f(fmaxf(ls[t], 1e-30f)); ls[t] = a; }
  }
  __syncthreads();
  if (tid < L_) cv[tid] = exp2f(ls[tid]);

  // ---- stage V^T bf16 ----
  {
    const int iL = tid & 7;
    const int sP = tid >> 3;
    const int s0 = sP * 2;
    const float* v0 = vbase + (size_t)s0 * D_;
    const float* v1 = vbase + (size_t)(s0 + 1) * D_;
#pragma unroll
    for (int pass = 0; pass < 8; ++pass) {
      const int i0 = pass * 32 + iL * 4;
      float va[4], vb[4];
      *(float4*)va = *(const float4*)(v0 + i0);
      *(float4*)vb = *(const float4*)(v1 + i0);
#pragma unroll
      for (int u = 0; u < 4; ++u)
        *(u32*)&VT[i0 + u][s0] = (u32)f2bf(va[u]) | ((u32)f2bf(vb[u]) << 16);
    }
  }

  const int lane = tid & 63, wave = tid >> 6;
  const int quad = lane >> 4, l15 = lane & 15;

  // ---- phase A: T = Q K^T,  wave w owns t-rows [w*16, w*16+16) ----
  {
    const int m0 = wave * 16;
    f4v accA[4];
#pragma unroll
    for (int nt = 0; nt < 4; ++nt) accA[nt] = (f4v){0.f, 0.f, 0.f, 0.f};
#pragma unroll
    for (int ksd = 0; ksd < 8; ++ksd) {
      const int d0 = ksd * 32 + quad * 8;
      const float* qrow = qbase + (size_t)(m0 + l15) * D_ + d0;
      const s8v af = pack8(*(const float4*)qrow, *(const float4*)(qrow + 4));
#pragma unroll
      for (int nt = 0; nt < 4; ++nt) {
        const float* krow = kbase + (size_t)(nt * 16 + l15) * D_ + d0;
        const s8v bf = pack8(*(const float4*)krow, *(const float4*)(krow + 4));
        accA[nt] = __builtin_amdgcn_mfma_f32_16x16x32_bf16(af, bf, accA[nt],
                                                           0, 0, 0);
      }
    }
#pragma unroll
    for (int nt = 0; nt < 4; ++nt)
#pragma unroll
      for (int r = 0; r < 4; ++r) {
        const int t = m0 + quad * 4 + r;
        const int s = nt * 16 + l15;
        const float m = (s <= t) ? exp2f(ls[t] - ls[s]) : 0.f;
        Tm[t][s] = accA[nt][r] * m;
      }
  }
  __syncthreads();

  // ---- phase B: wave w owns j-strip [w*64, w*64+64) ----
  const int j0w = wave * 64;
  f4v accS[4][4], accH[4][4];
#pragma unroll
  for (int mt = 0; mt < 4; ++mt)
#pragma unroll
    for (int nt = 0; nt < 4; ++nt) {
      accS[mt][nt] = (f4v){0.f, 0.f, 0.f, 0.f};
      accH[mt][nt] = (f4v){0.f, 0.f, 0.f, 0.f};
    }

  // Tm @ V   (inner s = 64)
#pragma unroll
  for (int ks = 0; ks < 2; ++ks) {
    const int so = ks * 32 + quad * 8;
    s8v af[4], bf[4];
#pragma unroll
    for (int mt = 0; mt < 4; ++mt) {
      const float* tp = &Tm[mt * 16 + l15][so];
      af[mt] = pack8(*(const float4*)tp, *(const float4*)(tp + 4));
    }
#pragma unroll
    for (int nt = 0; nt < 4; ++nt)
      bf[nt] = *(const s8v*)&VT[j0w + nt * 16 + l15][so];
#pragma unroll
    for (int mt = 0; mt < 4; ++mt)
#pragma unroll
      for (int nt = 0; nt < 4; ++nt)
        accS[mt][nt] = __builtin_amdgcn_mfma_f32_16x16x32_bf16(
            af[mt], bf[nt], accS[mt][nt], 0, 0, 0);
  }

  // Q @ H    (inner i = 256; H-frags straight from global bf16)
#pragma unroll
  for (int ks = 0; ks < 8; ++ks) {
    const int io = ks * 32 + quad * 8;
    s8v af[4], bf[4];
#pragma unroll
    for (int mt = 0; mt < 4; ++mt) {
      const float* qrow = qbase + (size_t)(mt * 16 + l15) * D_ + io;
      af[mt] = pack8(*(const float4*)qrow, *(const float4*)(qrow + 4));
    }
#pragma unroll
    for (int nt = 0; nt < 4; ++nt)
      bf[nt] = *(const s8v*)(Hb + (size_t)(j0w + nt * 16 + l15) * D_ + io);
#pragma unroll
    for (int mt = 0; mt < 4; ++mt)
#pragma unroll
      for (int nt = 0; nt < 4; ++nt)
        accH[mt][nt] = __builtin_amdgcn_mfma_f32_16x16x32_bf16(
            af[mt], bf[nt], accH[mt][nt], 0, 0, 0);
  }

  // epilogue: O = accS + c_t * accH
  float* ob = outg + ((size_t)b * S_ + (size_t)c * L_) * D_;
#pragma unroll
  for (int mt = 0; mt < 4; ++mt)
#pragma unroll
    for (int r = 0; r < 4; ++r) {
      const int t = mt * 16 + quad * 4 + r;
      const float ct = cv[t];
#pragma unroll
      for (int nt = 0; nt < 4; ++nt) {
        const int j = j0w + nt * 16 + l15;
        ob[(size_t)t * D_ + j] = accS[mt][nt][r] + ct * accH[mt][nt][r];
      }
    }
}

// ---------------------------------------------------------------------------
extern "C" void kernel_launch(void* const* d_in, const int* in_sizes, int n_in,
                              void* d_out, int out_size, void* d_ws,
                              size_t ws_size, hipStream_t stream) {
  const float* q = (const float*)d_in[0];
  const float* k = (const float*)d_in[1];
  const float* v = (const float*)d_in[2];
  const float* beta = (const float*)d_in[3];
  float* out = (float*)d_out;

  u16* A = (u16*)d_ws;                                   // 64 MiB bf16 state
  float* P = (float*)((char*)d_ws + (size_t)BC_ * D_ * D_ * sizeof(u16));

  ks_summary2<<<dim3(BC_), dim3(256), 0, stream>>>(k, v, beta, A, P);
  ks_scan2<<<dim3(512), dim3(256), 0, stream>>>(A, P);
  ks_output2<<<dim3(BC_), dim3(256), 0, stream>>>(q, k, v, beta, A, out);
}

// Round 3
// 186.747 us; speedup vs baseline: 1.7726x; 1.1599x over previous
//
#include <hip/hip_runtime.h>
#include <math.h>

// Delta-rule linear attention, chunked + MFMA bf16, bf16 state buffer.
// B=8, S=4096, D=256, L=64 -> C=64 chunks/batch, 512 chunks total.
// ws: A/H buffer [512][256][256] bf16 in TRANSPOSED [j][i] layout (64 MiB),
//     then P [512] f32.

#define B_ 8
#define S_ 4096
#define D_ 256
#define L_ 64
#define C_ (S_ / L_)
#define BC_ (B_ * C_)

typedef __attribute__((ext_vector_type(8))) short s8v;   // 8 bf16 (4 VGPR)
typedef __attribute__((ext_vector_type(4))) float f4v;   // MFMA acc
typedef unsigned short u16;
typedef unsigned int u32;

__device__ __forceinline__ u16 f2bf(float f) {           // RNE f32->bf16
  u32 u = __float_as_uint(f);
  u += 0x7FFF + ((u >> 16) & 1);
  return (u16)(u >> 16);
}
__device__ __forceinline__ s8v pack8(float4 a, float4 b) {
  s8v r;
  r[0] = (short)f2bf(a.x); r[1] = (short)f2bf(a.y);
  r[2] = (short)f2bf(a.z); r[3] = (short)f2bf(a.w);
  r[4] = (short)f2bf(b.x); r[5] = (short)f2bf(b.y);
  r[6] = (short)f2bf(b.z); r[7] = (short)f2bf(b.w);
  return r;
}

// ---------------------------------------------------------------------------
// Kernel 1: Astore[bc][j][i] = sum_s w_s k_s[i] v_s[j]  (bf16 out, [j][i])
//           P[bc] = prod_s beta_s.  512 thr / 8 waves, wave owns 32 j-cols.
// ---------------------------------------------------------------------------
__global__ __launch_bounds__(512, 4) void ks_summary3(
    const float* __restrict__ kg, const float* __restrict__ vg,
    const float* __restrict__ beta, u16* __restrict__ A,
    float* __restrict__ P)
{
  __shared__ float ls[L_];
  __shared__ __align__(16) u16 KT[D_][72];   // [i][s], w-scaled
  __shared__ __align__(16) u16 VT[D_][72];   // [j][s]

  const int bc = blockIdx.x;
  const int b = bc / C_, c = bc % C_;
  const int tid = threadIdx.x;
  const float* betap = beta + (size_t)b * S_ + (size_t)c * L_;
  const float* kbase = kg + ((size_t)b * S_ + (size_t)c * L_) * D_;
  const float* vbase = vg + ((size_t)b * S_ + (size_t)c * L_) * D_;

  if (tid < 64) {                       // wave0: parallel prefix log2 scan
    float x = log2f(fmaxf(betap[tid], 1e-30f));
#pragma unroll
    for (int off = 1; off < 64; off <<= 1) {
      float y = __shfl_up(x, off);
      if (tid >= off) x += y;
    }
    ls[tid] = x;
    if (tid == 63) P[bc] = exp2f(x);
  }
  __syncthreads();
  const float ltot = ls[63];

  // ---- stage transposed bf16 tiles: half 0 -> KT (scaled), half 1 -> VT ----
  {
    const int half = tid >> 8;
    const int t2 = tid & 255;
    const int iL = t2 & 7;              // i subgroup
    const int s0 = (t2 >> 3) * 2;       // s pair
    const float* src0 = (half == 0 ? kbase : vbase) + (size_t)s0 * D_;
    const float* src1 = src0 + D_;
    float w0 = 1.f, w1 = 1.f;
    if (half == 0) { w0 = exp2f(ltot - ls[s0]); w1 = exp2f(ltot - ls[s0 + 1]); }
    u16 (*dst)[72] = (half == 0) ? KT : VT;
#pragma unroll
    for (int p = 0; p < 8; ++p) {
      const int i0 = p * 32 + iL * 4;
      float a0[4], a1[4];
      *(float4*)a0 = *(const float4*)(src0 + i0);
      *(float4*)a1 = *(const float4*)(src1 + i0);
#pragma unroll
      for (int u = 0; u < 4; ++u)
        *(u32*)&dst[i0 + u][s0] =
            (u32)f2bf(a0[u] * w0) | ((u32)f2bf(a1[u] * w1) << 16);
    }
  }
  __syncthreads();

  const int lane = tid & 63, wave = tid >> 6;
  const int quad = lane >> 4, l15 = lane & 15;
  const int m0 = wave * 32;                 // j-strip for this wave
  u16* Ab = A + (size_t)bc * D_ * D_;

  for (int ng = 0; ng < 4; ++ng) {          // i-groups of 64
    f4v acc[2][4];
#pragma unroll
    for (int mt = 0; mt < 2; ++mt)
#pragma unroll
      for (int nt = 0; nt < 4; ++nt) acc[mt][nt] = (f4v){0.f, 0.f, 0.f, 0.f};

#pragma unroll
    for (int ks = 0; ks < 2; ++ks) {
      const int so = ks * 32 + quad * 8;
      s8v av[2], bv[4];
#pragma unroll
      for (int mt = 0; mt < 2; ++mt)
        av[mt] = *(const s8v*)&VT[m0 + mt * 16 + l15][so];
#pragma unroll
      for (int nt = 0; nt < 4; ++nt)
        bv[nt] = *(const s8v*)&KT[ng * 64 + nt * 16 + l15][so];
#pragma unroll
      for (int mt = 0; mt < 2; ++mt)
#pragma unroll
        for (int nt = 0; nt < 4; ++nt)
          acc[mt][nt] = __builtin_amdgcn_mfma_f32_16x16x32_bf16(
              av[mt], bv[nt], acc[mt][nt], 0, 0, 0);
    }
    // epilogue: bf16 pair-packed stores, [j][i]
#pragma unroll
    for (int mt = 0; mt < 2; ++mt)
#pragma unroll
      for (int r = 0; r < 4; ++r) {
        const int j = m0 + mt * 16 + quad * 4 + r;
#pragma unroll
        for (int nt = 0; nt < 4; ++nt) {
          const int i = ng * 64 + nt * 16 + l15;
          const float v = acc[mt][nt][r];
          const float o = __shfl_xor(v, 1);
          if (!(lane & 1)) {
            *(u32*)(Ab + (size_t)j * D_ + i) =
                (u32)f2bf(v) | ((u32)f2bf(o) << 16);
          }
        }
      }
  }
}

// ---------------------------------------------------------------------------
// Kernel 2: in-place chunk scan (bf16 state, fp32 accumulate), prefetched.
// 1024 blocks x 256 thr; one u32 (2 elems) per thread -> 16 waves/CU.
// ---------------------------------------------------------------------------
__global__ __launch_bounds__(256) void ks_scan3(
    u16* __restrict__ A, const float* __restrict__ P)
{
  const int g = blockIdx.x;
  const int b = g >> 7;                                 // 128 blocks / batch
  const int idx = ((g & 127) << 8) + threadIdx.x;       // u32 unit 0..32767
  u16* base = A + (size_t)b * ((size_t)C_ * D_ * D_) + (size_t)idx * 2;
  const float* Pb = P + b * C_;

  float h0 = 0.f, h1 = 0.f;
  u32 nxt = *(const u32*)base;
  float pn = Pb[0];
#pragma unroll 4
  for (int c = 0; c < C_; ++c) {
    const u32 u = nxt;
    const float pc = pn;
    u16* p = base + (size_t)c * (D_ * D_);
    if (c + 1 < C_) {                     // prefetch next chunk
      nxt = *(const u32*)(p + (size_t)(D_ * D_));
      pn = Pb[c + 1];
    }
    const float a0 = __uint_as_float(u << 16);
    const float a1 = __uint_as_float(u & 0xFFFF0000u);
    *(u32*)p = (u32)f2bf(h0) | ((u32)f2bf(h1) << 16);
    h0 = fmaf(pc, h0, a0);
    h1 = fmaf(pc, h1, a1);
  }
}

// ---------------------------------------------------------------------------
// Kernel 3: O = Tm @ V + diag(c) Q @ H.   512 thr / 8 waves.
//  stage QB,KB (bf16 row-major LDS) -> phase A: T=QK^T -> Tm (bf16 LDS)
//  -> stage V^T over KB's space -> phase B (wave owns 32 j-cols).
// ---------------------------------------------------------------------------
__global__ __launch_bounds__(512, 4) void ks_output3(
    const float* __restrict__ qg, const float* __restrict__ kg,
    const float* __restrict__ vg, const float* __restrict__ beta,
    const u16* __restrict__ Hg, float* __restrict__ outg)
{
  __shared__ float ls[L_];
  __shared__ float cv[L_];
  __shared__ __align__(16) u16 QB[L_][264];     // [t][d] bf16 (33792 B)
  __shared__ __align__(16) u16 UN[D_ * 72];     // union: KB[64][264] / VT[256][72]
  __shared__ __align__(16) u16 Tm[L_][72];      // [t][s] bf16
  u16 (*KB)[264] = (u16(*)[264])UN;
  u16 (*VT)[72] = (u16(*)[72])UN;

  const int bc = blockIdx.x;
  const int b = bc / C_, c = bc % C_;
  const int tid = threadIdx.x;
  const float* betap = beta + (size_t)b * S_ + (size_t)c * L_;
  const float* qbase = qg + ((size_t)b * S_ + (size_t)c * L_) * D_;
  const float* kbase = kg + ((size_t)b * S_ + (size_t)c * L_) * D_;
  const float* vbase = vg + ((size_t)b * S_ + (size_t)c * L_) * D_;
  const u16* Hb = Hg + (size_t)bc * D_ * D_;

  if (tid < 64) {                       // wave0: beta prefix scan
    float x = log2f(fmaxf(betap[tid], 1e-30f));
#pragma unroll
    for (int off = 1; off < 64; off <<= 1) {
      float y = __shfl_up(x, off);
      if (tid >= off) x += y;
    }
    ls[tid] = x;
  }

  // ---- stage QB (half 0) and KB (half 1), row-major bf16, b128 writes ----
  {
    const int half = tid >> 8;
    const int t2 = tid & 255;
    const int t = t2 >> 2;              // 0..63
    const int cg = (t2 & 3) * 8;
    const float* src = (half == 0 ? qbase : kbase) + (size_t)t * D_ + cg;
    u16 (*dst)[264] = (half == 0) ? QB : KB;
#pragma unroll
    for (int p = 0; p < 8; ++p) {
      const int c0 = cg + p * 32;
      const s8v pk =
          pack8(*(const float4*)(src + p * 32), *(const float4*)(src + p * 32 + 4));
      *(s8v*)&dst[t][c0] = pk;
    }
  }
  __syncthreads();
  if (tid < 64) cv[tid] = exp2f(ls[tid]);   // c_t

  const int lane = tid & 63, wave = tid >> 6;
  const int quad = lane >> 4, l15 = lane & 15;

  // ---- phase A: T = Q K^T ; wave w: t-tile (w&3), s-tiles {2(w>>2), +1} ----
  {
    const int mA = (wave & 3) * 16;
    const int nB = (wave >> 2) * 2;
    f4v accA[2];
#pragma unroll
    for (int i = 0; i < 2; ++i) accA[i] = (f4v){0.f, 0.f, 0.f, 0.f};
#pragma unroll
    for (int kd = 0; kd < 8; ++kd) {
      const int d0 = kd * 32 + quad * 8;
      const s8v af = *(const s8v*)&QB[mA + l15][d0];
#pragma unroll
      for (int i = 0; i < 2; ++i) {
        const s8v bf = *(const s8v*)&KB[(nB + i) * 16 + l15][d0];
        accA[i] = __builtin_amdgcn_mfma_f32_16x16x32_bf16(af, bf, accA[i],
                                                          0, 0, 0);
      }
    }
#pragma unroll
    for (int i = 0; i < 2; ++i)
#pragma unroll
      for (int r = 0; r < 4; ++r) {
        const int t = mA + quad * 4 + r;
        const int s = (nB + i) * 16 + l15;
        const float m = (s <= t) ? exp2f(ls[t] - ls[s]) : 0.f;
        Tm[t][s] = f2bf(accA[i][r] * m);
      }
  }
  __syncthreads();   // Tm ready; KB dead

  // ---- stage V^T bf16 over KB's space ----
  {
    const int iL = tid & 15;
    const int s0 = (tid >> 4) * 2;      // 0..62
#pragma unroll
    for (int p = 0; p < 4; ++p) {
      const int i0 = p * 64 + iL * 4;
      float a0[4], a1[4];
      *(float4*)a0 = *(const float4*)(vbase + (size_t)s0 * D_ + i0);
      *(float4*)a1 = *(const float4*)(vbase + (size_t)(s0 + 1) * D_ + i0);
#pragma unroll
      for (int u = 0; u < 4; ++u)
        *(u32*)&VT[i0 + u][s0] = (u32)f2bf(a0[u]) | ((u32)f2bf(a1[u]) << 16);
    }
  }
  __syncthreads();

  // ---- phase B: wave owns j-strip [wave*32, +32) ----
  const int j0w = wave * 32;
  f4v accS[4][2], accH[4][2];
#pragma unroll
  for (int mt = 0; mt < 4; ++mt)
#pragma unroll
    for (int nt = 0; nt < 2; ++nt) {
      accS[mt][nt] = (f4v){0.f, 0.f, 0.f, 0.f};
      accH[mt][nt] = (f4v){0.f, 0.f, 0.f, 0.f};
    }

  // Tm @ V  (inner s = 64)
#pragma unroll
  for (int ks = 0; ks < 2; ++ks) {
    const int so = ks * 32 + quad * 8;
    s8v af[4], bf[2];
#pragma unroll
    for (int mt = 0; mt < 4; ++mt)
      af[mt] = *(const s8v*)&Tm[mt * 16 + l15][so];
#pragma unroll
    for (int nt = 0; nt < 2; ++nt)
      bf[nt] = *(const s8v*)&VT[j0w + nt * 16 + l15][so];
#pragma unroll
    for (int mt = 0; mt < 4; ++mt)
#pragma unroll
      for (int nt = 0; nt < 2; ++nt)
        accS[mt][nt] = __builtin_amdgcn_mfma_f32_16x16x32_bf16(
            af[mt], bf[nt], accS[mt][nt], 0, 0, 0);
  }

  // Q @ H   (inner i = 256; H bf16 [j][i] from global, QB from LDS)
#pragma unroll
  for (int ks = 0; ks < 8; ++ks) {
    const int io = ks * 32 + quad * 8;
    s8v af[4], bf[2];
#pragma unroll
    for (int mt = 0; mt < 4; ++mt)
      af[mt] = *(const s8v*)&QB[mt * 16 + l15][io];
#pragma unroll
    for (int nt = 0; nt < 2; ++nt)
      bf[nt] = *(const s8v*)(Hb + (size_t)(j0w + nt * 16 + l15) * D_ + io);
#pragma unroll
    for (int mt = 0; mt < 4; ++mt)
#pragma unroll
      for (int nt = 0; nt < 2; ++nt)
        accH[mt][nt] = __builtin_amdgcn_mfma_f32_16x16x32_bf16(
            af[mt], bf[nt], accH[mt][nt], 0, 0, 0);
  }

  // epilogue: O = accS + c_t * accH
  float* ob = outg + ((size_t)b * S_ + (size_t)c * L_) * D_;
#pragma unroll
  for (int mt = 0; mt < 4; ++mt)
#pragma unroll
    for (int r = 0; r < 4; ++r) {
      const int t = mt * 16 + quad * 4 + r;
      const float ct = cv[t];
#pragma unroll
      for (int nt = 0; nt < 2; ++nt) {
        const int j = j0w + nt * 16 + l15;
        ob[(size_t)t * D_ + j] = accS[mt][nt][r] + ct * accH[mt][nt][r];
      }
    }
}

// ---------------------------------------------------------------------------
extern "C" void kernel_launch(void* const* d_in, const int* in_sizes, int n_in,
                              void* d_out, int out_size, void* d_ws,
                              size_t ws_size, hipStream_t stream) {
  const float* q = (const float*)d_in[0];
  const float* k = (const float*)d_in[1];
  const float* v = (const float*)d_in[2];
  const float* beta = (const float*)d_in[3];
  float* out = (float*)d_out;

  u16* A = (u16*)d_ws;                                   // 64 MiB bf16 state
  float* P = (float*)((char*)d_ws + (size_t)BC_ * D_ * D_ * sizeof(u16));

  ks_summary3<<<dim3(BC_), dim3(512), 0, stream>>>(k, v, beta, A, P);
  ks_scan3<<<dim3(1024), dim3(256), 0, stream>>>(A, P);
  ks_output3<<<dim3(BC_), dim3(512), 0, stream>>>(q, k, v, beta, A, out);
}